// Round 12
// baseline (438.226 us; speedup 1.0000x reference)
//
#include <hip/hip_runtime.h>
#include <hip/hip_bf16.h>
#include <math.h>

#define NN     10000
#define EE     320000
#define IN_CH  739
#define CC     64
#define GG     64
#define NLAYER 9
#define NBUCK  157    // ceil(NN/64)
#define CHUNK  2048   // edges per k_part1 block
#define KSPLIT 12     // gemm1 K-split: 12 chunks of 64 (739 -> 11x64+35)
#define GEMM1B (157 * KSPLIT)   // 1884 gemm blocks
#define HISTB  157              // hist blocks: 157 * 2048 edges >= EE

typedef _Float16 half_t;
typedef _Float16 h4 __attribute__((ext_vector_type(4)));

// fast elu / softplus: |abs err| ~1e-7 vs libm, threshold is 4.5e-4
__device__ __forceinline__ float eluf(float x) {
    return x > 0.f ? x : __expf(x) - 1.f;
}
__device__ __forceinline__ float softplusf(float x) {
    return fmaxf(x, 0.f) + __logf(1.f + __expf(-fabsf(x)));
}
__device__ __forceinline__ float wave_sum(float v) {
#pragma unroll
    for (int off = 32; off > 0; off >>= 1) v += __shfl_xor(v, off, 64);
    return v;
}
// 8B fp16x4 gather load -> fp32
__device__ __forceinline__ float4 ldh4(const half_t* p) {
    const h4 v = *(const h4*)p;
    return make_float4((float)v.x, (float)v.y, (float)v.z, (float)v.w);
}

// ---------------------------------------------------------------------------
// GEMM1 (blocks 0..1883: tile x 12 K-chunks of 64, SINGLE stage, one barrier)
// + edge histogram (blocks 1884..2040, 8 edges/thread).
// 12-way split -> 3x blocks in flight vs the old 4-way 3-stage version,
// no serial K-stages, so global-load latency hides across blocks.
// ---------------------------------------------------------------------------
__global__ __launch_bounds__(256) void k_gemm1_hist(
    const float* __restrict__ x, const float* __restrict__ w0,
    float* __restrict__ hpart,
    const int* __restrict__ ei, int* __restrict__ deg)
{
    __shared__ float xs[64 * 68];   // [row][k], stride 68
    __shared__ float ws[64 * 64];   // [k][col]

    if (blockIdx.x >= GEMM1B) {     // histogram tail
        const int base = (blockIdx.x - GEMM1B) * 2048 + threadIdx.x;
#pragma unroll
        for (int j = 0; j < 8; ++j) {
            const int e = base + 256 * j;
            if (e < EE) atomicAdd(&deg[ei[EE + e]], 1);
        }
        return;
    }

    const int tid = threadIdx.x;
    const int split = blockIdx.x % KSPLIT;
    const int tile  = blockIdx.x / KSPLIT;
    const int R0 = tile * 64;
    const int K0 = split * 64;

    const int sk = tid & 63;
    const int sr = tid >> 6;

#pragma unroll
    for (int i = 0; i < 16; ++i) {
        const int r = sr + 4 * i;
        const int gr = R0 + r;
        const int gk = K0 + sk;
        xs[r * 68 + sk] = (gr < NN && gk < IN_CH)
                              ? x[(size_t)gr * IN_CH + gk] : 0.f;
        const int wk = K0 + r;
        ws[r * 64 + sk] = (wk < IN_CH) ? w0[wk * CC + sk] : 0.f;
    }
    __syncthreads();

    const int cg = tid & 15;
    const int rg = tid >> 4;
    float acc[4][4] = {};
#pragma unroll 4
    for (int k4 = 0; k4 < 64; k4 += 4) {
        float4 xv[4], wv[4];
#pragma unroll
        for (int j = 0; j < 4; ++j)
            xv[j] = *(const float4*)&xs[(rg * 4 + j) * 68 + k4];
#pragma unroll
        for (int q = 0; q < 4; ++q)
            wv[q] = *(const float4*)&ws[(k4 + q) * 64 + cg * 4];
#pragma unroll
        for (int j = 0; j < 4; ++j) {
            const float* xf = (const float*)&xv[j];
#pragma unroll
            for (int q = 0; q < 4; ++q) {
                const float* wf = (const float*)&wv[q];
#pragma unroll
                for (int i = 0; i < 4; ++i)
                    acc[j][i] = fmaf(xf[q], wf[i], acc[j][i]);
            }
        }
    }

#pragma unroll
    for (int j = 0; j < 4; ++j) {
        const int row = R0 + rg * 4 + j;
        if (row < NN)
            *(float4*)&hpart[((size_t)split * NN + row) * CC + cg * 4] =
                make_float4(acc[j][0], acc[j][1], acc[j][2], acc[j][3]);
    }
}

// ---------------------------------------------------------------------------
// Init stage 2 (blocks 0..312: sum 12 partials + b0, elu, GEMM2, hop-attn z0)
// + deg-scan (block 313) + graph bounds (blocks 314..353).
// ---------------------------------------------------------------------------
__global__ __launch_bounds__(256) void k_init2_scan(
    const float* __restrict__ hpart,
    const float* __restrict__ b0, const float* __restrict__ w1,
    const float* __restrict__ b1,
    const float* __restrict__ hop_att0, const float* __restrict__ hop_bias0,
    float scale1,
    half_t* __restrict__ xout, float* __restrict__ zout,
    float* __restrict__ zsout, half_t* __restrict__ zshout,
    const int* __restrict__ deg, int* __restrict__ offs,
    int* __restrict__ bcur,
    const int* __restrict__ batch, int* __restrict__ gstart)
{
    __shared__ float xs[32 * 68];
    __shared__ float ws[64 * 64];
    __shared__ int part[256];
    const int tid = threadIdx.x;

    if (blockIdx.x == 313) {         // deg exclusive scan + bucket bases
        const int start = tid * 40;
        const int end = start + 40 < NN ? start + 40 : NN;
        int sum = 0;
        for (int i = start; i < end; ++i) sum += deg[i];
        part[tid] = sum;
        __syncthreads();
        if (tid == 0) {
            int run = 0;
            for (int i = 0; i < 256; ++i) { int t = part[i]; part[i] = run; run += t; }
        }
        __syncthreads();
        int run = part[tid];
        for (int i = start; i < end; ++i) {
            offs[i] = run;
            if ((i & 63) == 0) bcur[i >> 6] = run;
            run += deg[i];
        }
        return;
    }
    if (blockIdx.x > 313) {          // graph boundary detection
        const int n = (blockIdx.x - 314) * 256 + tid;
        if (n >= NN) return;
        if (n == 0)
            for (int g = 0; g <= batch[0]; ++g) gstart[g] = 0;
        else {
            const int b0_ = batch[n - 1], b1_ = batch[n];
            for (int g = b0_ + 1; g <= b1_; ++g) gstart[g] = n;
        }
        if (n == NN - 1)
            for (int g = batch[NN - 1] + 1; g <= GG; ++g) gstart[g] = NN;
        return;
    }

    const int R0 = blockIdx.x * 32;

#pragma unroll
    for (int j = 0; j < 2; ++j) {
        const int slot = tid + 256 * j;       // 512 float4 slots
        const int row = slot >> 4;
        const int col4 = (slot & 15) * 4;
        const int grow = R0 + row;
        float4 s = make_float4(0.f, 0.f, 0.f, 0.f);
        if (grow < NN) {
#pragma unroll
            for (int sp = 0; sp < KSPLIT; ++sp) {
                const float4 v =
                    *(const float4*)&hpart[((size_t)sp * NN + grow) * CC + col4];
                s.x += v.x; s.y += v.y; s.z += v.z; s.w += v.w;
            }
        }
        const float4 bb = *(const float4*)&b0[col4];
        s.x = eluf(s.x + bb.x); s.y = eluf(s.y + bb.y);
        s.z = eluf(s.z + bb.z); s.w = eluf(s.w + bb.w);
        *(float4*)&xs[row * 68 + col4] = s;
    }
    {
        const int sk = tid & 63;
        const int sr = tid >> 6;
#pragma unroll
        for (int i = 0; i < 16; ++i)
            ws[(sr + 4 * i) * 64 + sk] = w1[(sr + 4 * i) * CC + sk];
    }
    __syncthreads();

    const int cg = tid & 15;
    const int rg = tid >> 4;
    float acc2[2][4];
    const float4 b1v = *(const float4*)&b1[cg * 4];
#pragma unroll
    for (int j = 0; j < 2; ++j) {
        acc2[j][0] = b1v.x; acc2[j][1] = b1v.y;
        acc2[j][2] = b1v.z; acc2[j][3] = b1v.w;
    }
#pragma unroll 4
    for (int k4 = 0; k4 < 64; k4 += 4) {
        float4 xv[2], wv[4];
#pragma unroll
        for (int j = 0; j < 2; ++j)
            xv[j] = *(const float4*)&xs[(rg * 2 + j) * 68 + k4];
#pragma unroll
        for (int q = 0; q < 4; ++q)
            wv[q] = *(const float4*)&ws[(k4 + q) * 64 + cg * 4];
#pragma unroll
        for (int j = 0; j < 2; ++j) {
            const float* xf = (const float*)&xv[j];
#pragma unroll
            for (int q = 0; q < 4; ++q) {
                const float* wf = (const float*)&wv[q];
#pragma unroll
                for (int i = 0; i < 4; ++i)
                    acc2[j][i] = fmaf(xf[q], wf[i], acc2[j][i]);
            }
        }
    }

    __syncthreads();
#pragma unroll
    for (int j = 0; j < 2; ++j)
        *(float4*)&ws[(rg * 2 + j) * 64 + cg * 4] =
            make_float4(acc2[j][0], acc2[j][1], acc2[j][2], acc2[j][3]);
    __syncthreads();

    const int c = tid & 63;
    const int w = tid >> 6;
    const float ha = hop_att0[c];
    const float hb = hop_bias0[0];
#pragma unroll
    for (int rr = 0; rr < 8; ++rr) {
        const int r = w * 8 + rr;
        const float v = ws[r * 64 + c];
        const float attn = wave_sum(ha * eluf(v)) + hb;
        const int row = R0 + r;
        if (row < NN) {
            const float zv = v * attn;
            const float zs = zv * scale1;
            xout[row * CC + c] = (half_t)v;
            zout[row * CC + c] = zv;
            zsout[row * CC + c] = zs;
            zshout[row * CC + c] = (half_t)zs;
        }
    }
}

// pass 1: partition edges into 157 coarse buckets (dst>>6), pairs (src,dst).
__global__ __launch_bounds__(256) void k_part1(
    const int* __restrict__ ei, int* __restrict__ bcur,
    int2* __restrict__ csr_pair)
{
    __shared__ int hist[NBUCK];
    __shared__ int scan_s[NBUCK];
    __shared__ int base_g[NBUCK];
    __shared__ int lcur[NBUCK];
    __shared__ int2 staged[CHUNK];
    const int tid = threadIdx.x;
    const int e0 = blockIdx.x * CHUNK;

    for (int b = tid; b < NBUCK; b += 256) { hist[b] = 0; lcur[b] = 0; }
    __syncthreads();

    int src[8], dst[8];
#pragma unroll
    for (int j = 0; j < 8; ++j) {
        const int e = e0 + tid + 256 * j;
        if (e < EE) {
            src[j] = ei[e];
            dst[j] = ei[EE + e];
            atomicAdd(&hist[dst[j] >> 6], 1);
        } else dst[j] = -1;
    }
    __syncthreads();
    if (tid == 0) {
        int run = 0;
        for (int b = 0; b < NBUCK; ++b) { scan_s[b] = run; run += hist[b]; }
    }
    __syncthreads();
    if (tid < NBUCK && hist[tid] > 0)
        base_g[tid] = atomicAdd(&bcur[tid], hist[tid]);
    __syncthreads();
#pragma unroll
    for (int j = 0; j < 8; ++j) {
        if (dst[j] >= 0) {
            const int b = dst[j] >> 6;
            const int r = atomicAdd(&lcur[b], 1);
            staged[scan_s[b] + r] = make_int2(src[j], dst[j]);
        }
    }
    __syncthreads();
    const int tot = (EE - e0) < CHUNK ? (EE - e0) : CHUNK;
    for (int i = tid; i < tot; i += 256) {
        const int2 p = staged[i];
        const int b = p.y >> 6;
        csr_pair[base_g[b] + (i - scan_s[b])] = p;
    }
}

// pass 2: within each bucket, place each edge at its exact CSR slot.
__global__ __launch_bounds__(256) void k_part2(
    const int* __restrict__ offs, const int2* __restrict__ csr_pair,
    int* __restrict__ csr_src)
{
    __shared__ int lcnt[64];
    __shared__ int loffs[64];
    const int b = blockIdx.x;           // NBUCK blocks
    const int tid = threadIdx.x;
    const int d0 = b * 64;
    if (tid < 64) {
        lcnt[tid] = 0;
        const int d = d0 + tid;
        loffs[tid] = (d < NN) ? offs[d] : EE;
    }
    __syncthreads();
    const int r0 = offs[d0];
    const int r1 = (d0 + 64 < NN) ? offs[d0 + 64] : EE;
    for (int i = r0 + tid; i < r1; i += 256) {
        const int2 p = csr_pair[i];
        const int ld = p.y & 63;
        const int r = atomicAdd(&lcnt[ld], 1);
        csr_src[loffs[ld] + r] = p.x;
    }
}

// ---------------------------------------------------------------------------
// Fused edge attention + degree norm. One wave per block, one node, grid=NN.
// zs gathers fp16 (zsh); per-node zd fp32 (zsbuf) — r10-proven split.
// ---------------------------------------------------------------------------
__global__ __launch_bounds__(64) void k_edge_adj(
    const int* __restrict__ offs, const int* __restrict__ deg,
    const int* __restrict__ csr_src,
    const float* __restrict__ zs_buf, const half_t* __restrict__ zsh,
    const float* __restrict__ conv_att,
    float* __restrict__ a_csr, float* __restrict__ inv_adj)
{
    const int n = blockIdx.x;
    const int lane = threadIdx.x;
    const int l = lane & 15;
    const int grp = lane >> 4;
    const int start = offs[n];
    const int len = deg[n];

    const float4 zd = *(const float4*)(zs_buf + n * CC + l * 4);
    const float4 scv = *(const float4*)(conv_att + l * 4);

    float asum = 0.f;
    int i = grp;
    for (; i + 12 < len; i += 16) {      // 4 edges in flight per group
        const int s0 = csr_src[start + i];
        const int s1 = csr_src[start + i + 4];
        const int s2 = csr_src[start + i + 8];
        const int s3 = csr_src[start + i + 12];
        const float4 a0 = ldh4(zsh + s0 * CC + l * 4);
        const float4 a1 = ldh4(zsh + s1 * CC + l * 4);
        const float4 a2 = ldh4(zsh + s2 * CC + l * 4);
        const float4 a3 = ldh4(zsh + s3 * CC + l * 4);
        float p0 = scv.x * eluf(a0.x + zd.x);
        p0 = fmaf(scv.y, eluf(a0.y + zd.y), p0);
        p0 = fmaf(scv.z, eluf(a0.z + zd.z), p0);
        p0 = fmaf(scv.w, eluf(a0.w + zd.w), p0);
        float p1 = scv.x * eluf(a1.x + zd.x);
        p1 = fmaf(scv.y, eluf(a1.y + zd.y), p1);
        p1 = fmaf(scv.z, eluf(a1.z + zd.z), p1);
        p1 = fmaf(scv.w, eluf(a1.w + zd.w), p1);
        float p2 = scv.x * eluf(a2.x + zd.x);
        p2 = fmaf(scv.y, eluf(a2.y + zd.y), p2);
        p2 = fmaf(scv.z, eluf(a2.z + zd.z), p2);
        p2 = fmaf(scv.w, eluf(a2.w + zd.w), p2);
        float p3 = scv.x * eluf(a3.x + zd.x);
        p3 = fmaf(scv.y, eluf(a3.y + zd.y), p3);
        p3 = fmaf(scv.z, eluf(a3.z + zd.z), p3);
        p3 = fmaf(scv.w, eluf(a3.w + zd.w), p3);
#pragma unroll
        for (int off = 8; off > 0; off >>= 1) {
            p0 += __shfl_xor(p0, off, 64);
            p1 += __shfl_xor(p1, off, 64);
            p2 += __shfl_xor(p2, off, 64);
            p3 += __shfl_xor(p3, off, 64);
        }
        const float ae0 = softplusf(p0) + 1e-6f;
        const float ae1 = softplusf(p1) + 1e-6f;
        const float ae2 = softplusf(p2) + 1e-6f;
        const float ae3 = softplusf(p3) + 1e-6f;
        asum += ae0 + ae1 + ae2 + ae3;
        if (l == 0) {
            a_csr[start + i] = ae0;
            a_csr[start + i + 4] = ae1;
            a_csr[start + i + 8] = ae2;
            a_csr[start + i + 12] = ae3;
        }
    }
    for (; i < len; i += 4) {
        const int s0 = csr_src[start + i];
        const float4 a0 = ldh4(zsh + s0 * CC + l * 4);
        float p0 = scv.x * eluf(a0.x + zd.x);
        p0 = fmaf(scv.y, eluf(a0.y + zd.y), p0);
        p0 = fmaf(scv.z, eluf(a0.z + zd.z), p0);
        p0 = fmaf(scv.w, eluf(a0.w + zd.w), p0);
#pragma unroll
        for (int off = 8; off > 0; off >>= 1) p0 += __shfl_xor(p0, off, 64);
        const float ae0 = softplusf(p0) + 1e-6f;
        asum += ae0;
        if (l == 0) a_csr[start + i] = ae0;
    }

    asum += __shfl_xor(asum, 16, 64);
    asum += __shfl_xor(asum, 32, 64);
    if (lane == 0) inv_adj[n] = rsqrtf(fmaxf(asum, 1e-32f));
}

// ---------------------------------------------------------------------------
// Fused message gather + UpdateZ. One wave per block, one node, grid=NN.
// 8 row-gathers in flight; x gathers fp16. (r10-proven version)
// ---------------------------------------------------------------------------
__global__ __launch_bounds__(64) void k_msg_fused(
    const int* __restrict__ offs, const int* __restrict__ deg,
    const int* __restrict__ csr_src, const float* __restrict__ a_csr,
    const float* __restrict__ inv_adj, const half_t* __restrict__ x,
    half_t* __restrict__ xn, float* __restrict__ z,
    float* __restrict__ zs_buf, half_t* __restrict__ zsh,
    const float* __restrict__ hop_att, const float* __restrict__ hop_bias,
    float scale_next)
{
    const int n = blockIdx.x;
    const int c = threadIdx.x;
    const int start = offs[n];
    const int len = deg[n];
    const float invd = inv_adj[n];

    float acc = 0.f;
    for (int base = 0; base < len; base += 64) {
        const int cnt = (len - base) < 64 ? (len - base) : 64;
        int s_l = 0; float na_l = 0.f;
        if (c < cnt) {
            s_l = csr_src[start + base + c];
            na_l = a_csr[start + base + c] * inv_adj[s_l] * invd;
        }
        int j = 0;
        for (; j + 8 <= cnt; j += 8) {
            int ss[8]; float nn_[8];
#pragma unroll
            for (int q = 0; q < 8; ++q) {
                ss[q] = __builtin_amdgcn_readlane(s_l, j + q);
                nn_[q] = __int_as_float(
                    __builtin_amdgcn_readlane(__float_as_int(na_l), j + q));
            }
            float vv[8];
#pragma unroll
            for (int q = 0; q < 8; ++q) vv[q] = (float)x[ss[q] * CC + c];
#pragma unroll
            for (int q = 0; q < 8; ++q) acc = fmaf(vv[q], nn_[q], acc);
        }
        for (; j < cnt; ++j) {
            const int s = __builtin_amdgcn_readlane(s_l, j);
            const float na = __int_as_float(
                __builtin_amdgcn_readlane(__float_as_int(na_l), j));
            acc = fmaf((float)x[s * CC + c], na, acc);
        }
    }

    // UpdateZ (k >= 1): g = [h, z_scale]; z_scale is zs (already scaled)
    const float zv = z[n * CC + c];
    const float zsv = zs_buf[n * CC + c];
    float g = hop_att[c] * eluf(acc) + hop_att[CC + c] * eluf(zsv);
    const float attn = wave_sum(g) + hop_bias[0];
    const float znew = zv + acc * attn;
    const float zsnew = znew * scale_next;
    z[n * CC + c] = znew;
    zs_buf[n * CC + c] = zsnew;
    zsh[n * CC + c] = (half_t)zsnew;
    xn[n * CC + c] = (half_t)acc;
}

// ---------------------------------------------------------------------------
// Fused readout: block per graph.
// ---------------------------------------------------------------------------
__global__ __launch_bounds__(256) void k_pool_head(
    const float* __restrict__ z, const int* __restrict__ gstart,
    const float* __restrict__ w_head, const float* __restrict__ b_head,
    float* __restrict__ out)
{
    __shared__ float red[4][CC];
    const int g = blockIdx.x;
    const int w = threadIdx.x >> 6;
    const int c = threadIdx.x & 63;
    const int s0 = gstart[g], s1 = gstart[g + 1];

    float acc = 0.f;
    for (int n = s0 + w; n < s1; n += 4) acc += eluf(z[n * CC + c]);
    red[w][c] = acc;
    __syncthreads();
    if (w == 0) {
        const float v = red[0][c] + red[1][c] + red[2][c] + red[3][c];
        const float tot = wave_sum(v * w_head[c]);
        if (c == 0)
            out[g] = tot / fmaxf((float)(s1 - s0), 1.f) + b_head[0];
    }
}

extern "C" void kernel_launch(void* const* d_in, const int* in_sizes, int n_in,
                              void* d_out, int out_size, void* d_ws, size_t ws_size,
                              hipStream_t stream) {
    const float* x        = (const float*)d_in[0];
    const int*   ei       = (const int*)d_in[1];
    const int*   batch    = (const int*)d_in[2];
    const float* w0       = (const float*)d_in[3];
    const float* b0       = (const float*)d_in[4];
    const float* w1       = (const float*)d_in[5];
    const float* b1       = (const float*)d_in[6];
    const float* conv_att = (const float*)d_in[7];
    const float* hop_att0 = (const float*)d_in[8];
    const float* hop_bias0= (const float*)d_in[9];
    const float* hop_att  = (const float*)d_in[10];
    const float* hop_bias = (const float*)d_in[11];
    const float* w_head   = (const float*)d_in[12];
    const float* b_head   = (const float*)d_in[13];
    float* out = (float*)d_out;

    float sc[NLAYER + 1];
    for (int k = 1; k <= NLAYER; ++k)
        sc[k] = (float)log(1.0 / (double)k + 1.0 + 1e-6);

    // ---- flat workspace layout ----
    float* zbuf    = (float*)d_ws;               // NN*CC fp32
    float* zsbuf   = zbuf + NN * CC;             // NN*CC fp32
    float* inv_adj = zsbuf + NN * CC;            // NN
    float* hpart   = inv_adj + NN;               // KSPLIT*NN*CC
    float* a_csr   = hpart + (size_t)KSPLIT * NN * CC;  // EE
    int*   csr_src = (int*)(a_csr + EE);         // EE
    int2*  csr_pair= (int2*)(csr_src + EE);      // EE pairs
    int*   deg     = (int*)(csr_pair + EE);      // NN (zeroed)
    int*   offs    = deg + NN;                   // NN
    int*   bcur    = offs + NN;                  // NBUCK
    int*   gstart  = bcur + NBUCK;               // GG+1
    half_t* xhA = (half_t*)(gstart + GG + 1);    // NN*CC fp16
    half_t* xhB = xhA + NN * CC;                 // NN*CC fp16
    half_t* zsh = xhB + NN * CC;                 // NN*CC fp16

    (void)hipMemsetAsync(deg, 0, (size_t)NN * 4, stream);
    k_gemm1_hist<<<GEMM1B + HISTB, 256, 0, stream>>>(x, w0, hpart, ei, deg);
    k_init2_scan<<<314 + (NN + 255) / 256, 256, 0, stream>>>(
        hpart, b0, w1, b1, hop_att0, hop_bias0, sc[1],
        xhA, zbuf, zsbuf, zsh, deg, offs, bcur, batch, gstart);
    k_part1<<<(EE + CHUNK - 1) / CHUNK, 256, 0, stream>>>(ei, bcur, csr_pair);
    k_part2<<<NBUCK, 256, 0, stream>>>(offs, csr_pair, csr_src);

    half_t* xcur = xhA;
    half_t* xnext = xhB;
    for (int i = 0; i < NLAYER; ++i) {
        const float scale_next = (i + 1 < NLAYER) ? sc[i + 2] : 0.f;
        k_edge_adj<<<NN, 64, 0, stream>>>(offs, deg, csr_src, zsbuf, zsh,
                                          conv_att + i * CC,
                                          a_csr, inv_adj);
        k_msg_fused<<<NN, 64, 0, stream>>>(offs, deg, csr_src, a_csr,
                                           inv_adj, xcur, xnext, zbuf,
                                           zsbuf, zsh,
                                           hop_att + i * 2 * CC,
                                           hop_bias + i, scale_next);
        half_t* t = xcur; xcur = xnext; xnext = t;
    }

    k_pool_head<<<GG, 256, 0, stream>>>(zbuf, gstart, w_head, b_head, out);
}

// Round 13
// 415.731 us; speedup vs baseline: 1.0541x; 1.0541x over previous
//
#include <hip/hip_runtime.h>
#include <hip/hip_bf16.h>
#include <math.h>

#define NN     10000
#define EE     320000
#define IN_CH  739
#define CC     64
#define GG     64
#define NLAYER 9
#define NBUCK  157    // ceil(NN/64)
#define CHUNK  2048   // edges per k_part1 block
#define KSPLIT 4      // gemm1 K-split (192 per split, 3 stages of 64)
#define TILES  313    // ceil(NN/32) row tiles of 32
#define GEMM1B (TILES * KSPLIT)   // 1252 gemm blocks (4.9/CU)
#define HISTB  157                // hist blocks: 157 * 2048 edges >= EE

typedef _Float16 half_t;
typedef _Float16 h4 __attribute__((ext_vector_type(4)));

// fast elu / softplus: |abs err| ~1e-7 vs libm, threshold is 4.5e-4
__device__ __forceinline__ float eluf(float x) {
    return x > 0.f ? x : __expf(x) - 1.f;
}
__device__ __forceinline__ float softplusf(float x) {
    return fmaxf(x, 0.f) + __logf(1.f + __expf(-fabsf(x)));
}
__device__ __forceinline__ float wave_sum(float v) {
#pragma unroll
    for (int off = 32; off > 0; off >>= 1) v += __shfl_xor(v, off, 64);
    return v;
}
// 8B fp16x4 gather load -> fp32
__device__ __forceinline__ float4 ldh4(const half_t* p) {
    const h4 v = *(const h4*)p;
    return make_float4((float)v.x, (float)v.y, (float)v.z, (float)v.w);
}

// ---------------------------------------------------------------------------
// GEMM1 (blocks 0..1251: 32-row tile x 4 K-splits of 192, 3 pipelined stages)
// + edge histogram (blocks 1252..1408, 8 edges/thread).
// vs r10: tile 64->32 rows doubles blocks in flight (2.45->4.9/CU) and cuts
// LDS 33.8->24.7KB, attacking the measured latency/occupancy limit while
// keeping hpart write traffic identical (KSPLIT=4, r12's regression cause).
// ---------------------------------------------------------------------------
__global__ __launch_bounds__(256) void k_gemm1_hist(
    const float* __restrict__ x, const float* __restrict__ w0,
    float* __restrict__ hpart,
    const int* __restrict__ ei, int* __restrict__ deg)
{
    __shared__ float xs[32 * 68];   // [row][k], stride 68
    __shared__ float ws[64 * 64];   // [k][col]

    if (blockIdx.x >= GEMM1B) {     // histogram tail
        const int base = (blockIdx.x - GEMM1B) * 2048 + threadIdx.x;
#pragma unroll
        for (int j = 0; j < 8; ++j) {
            const int e = base + 256 * j;
            if (e < EE) atomicAdd(&deg[ei[EE + e]], 1);
        }
        return;
    }

    const int tid = threadIdx.x;
    const int split = blockIdx.x & 3;
    const int tile  = blockIdx.x >> 2;
    const int R0 = tile * 32;
    const int K0 = split * 192;

    const int sk = tid & 63;
    const int sr = tid >> 6;

    float xr[8], wr[16];
    float acc[2][4] = {};

#pragma unroll
    for (int i = 0; i < 8; ++i) {
        const int r = sr + 4 * i;          // 32 x-rows
        const int gr = R0 + r;
        const int gk = K0 + sk;
        xr[i] = (gr < NN && gk < IN_CH) ? x[(size_t)gr * IN_CH + gk] : 0.f;
    }
#pragma unroll
    for (int i = 0; i < 16; ++i) {
        const int wk = K0 + sr + 4 * i;    // 64 w-rows
        wr[i] = (wk < IN_CH) ? w0[wk * CC + sk] : 0.f;
    }

    for (int t = 0; t < 3; ++t) {
        __syncthreads();
#pragma unroll
        for (int i = 0; i < 8; ++i)
            xs[(sr + 4 * i) * 68 + sk] = xr[i];
#pragma unroll
        for (int i = 0; i < 16; ++i)
            ws[(sr + 4 * i) * 64 + sk] = wr[i];
        __syncthreads();
        if (t + 1 < 3) {
            const int k0 = K0 + (t + 1) * 64;
#pragma unroll
            for (int i = 0; i < 8; ++i) {
                const int r = sr + 4 * i;
                const int gr = R0 + r;
                const int gk = k0 + sk;
                xr[i] = (gr < NN && gk < IN_CH) ? x[(size_t)gr * IN_CH + gk]
                                                : 0.f;
            }
#pragma unroll
            for (int i = 0; i < 16; ++i) {
                const int wk = k0 + sr + 4 * i;
                wr[i] = (wk < IN_CH) ? w0[wk * CC + sk] : 0.f;
            }
        }
        const int cg = tid & 15;
        const int rg = tid >> 4;
#pragma unroll 4
        for (int k4 = 0; k4 < 64; k4 += 4) {
            float4 xv[2], wv[4];
#pragma unroll
            for (int j = 0; j < 2; ++j)
                xv[j] = *(const float4*)&xs[(rg * 2 + j) * 68 + k4];
#pragma unroll
            for (int q = 0; q < 4; ++q)
                wv[q] = *(const float4*)&ws[(k4 + q) * 64 + cg * 4];
#pragma unroll
            for (int j = 0; j < 2; ++j) {
                const float* xf = (const float*)&xv[j];
#pragma unroll
                for (int q = 0; q < 4; ++q) {
                    const float* wf = (const float*)&wv[q];
#pragma unroll
                    for (int i = 0; i < 4; ++i)
                        acc[j][i] = fmaf(xf[q], wf[i], acc[j][i]);
                }
            }
        }
    }

    {
        const int cg = tid & 15;
        const int rg = tid >> 4;
#pragma unroll
        for (int j = 0; j < 2; ++j) {
            const int row = R0 + rg * 2 + j;
            if (row < NN)
                *(float4*)&hpart[((size_t)split * NN + row) * CC + cg * 4] =
                    make_float4(acc[j][0], acc[j][1], acc[j][2], acc[j][3]);
        }
    }
}

// ---------------------------------------------------------------------------
// Init stage 2 (blocks 0..312: sum 4 partials + b0, elu, GEMM2, hop-attn z0)
// + deg-scan (block 313) + graph bounds (blocks 314..353).
// ---------------------------------------------------------------------------
__global__ __launch_bounds__(256) void k_init2_scan(
    const float* __restrict__ hpart,
    const float* __restrict__ b0, const float* __restrict__ w1,
    const float* __restrict__ b1,
    const float* __restrict__ hop_att0, const float* __restrict__ hop_bias0,
    float scale1,
    half_t* __restrict__ xout, float* __restrict__ zout,
    float* __restrict__ zsout, half_t* __restrict__ zshout,
    const int* __restrict__ deg, int* __restrict__ offs,
    int* __restrict__ bcur,
    const int* __restrict__ batch, int* __restrict__ gstart)
{
    __shared__ float xs[32 * 68];
    __shared__ float ws[64 * 64];
    __shared__ int part[256];
    const int tid = threadIdx.x;

    if (blockIdx.x == 313) {         // deg exclusive scan + bucket bases
        const int start = tid * 40;
        const int end = start + 40 < NN ? start + 40 : NN;
        int sum = 0;
        for (int i = start; i < end; ++i) sum += deg[i];
        part[tid] = sum;
        __syncthreads();
        if (tid == 0) {
            int run = 0;
            for (int i = 0; i < 256; ++i) { int t = part[i]; part[i] = run; run += t; }
        }
        __syncthreads();
        int run = part[tid];
        for (int i = start; i < end; ++i) {
            offs[i] = run;
            if ((i & 63) == 0) bcur[i >> 6] = run;
            run += deg[i];
        }
        return;
    }
    if (blockIdx.x > 313) {          // graph boundary detection
        const int n = (blockIdx.x - 314) * 256 + tid;
        if (n >= NN) return;
        if (n == 0)
            for (int g = 0; g <= batch[0]; ++g) gstart[g] = 0;
        else {
            const int b0_ = batch[n - 1], b1_ = batch[n];
            for (int g = b0_ + 1; g <= b1_; ++g) gstart[g] = n;
        }
        if (n == NN - 1)
            for (int g = batch[NN - 1] + 1; g <= GG; ++g) gstart[g] = NN;
        return;
    }

    const int R0 = blockIdx.x * 32;

#pragma unroll
    for (int j = 0; j < 2; ++j) {
        const int slot = tid + 256 * j;       // 512 float4 slots
        const int row = slot >> 4;
        const int col4 = (slot & 15) * 4;
        const int grow = R0 + row;
        float4 s = make_float4(0.f, 0.f, 0.f, 0.f);
        if (grow < NN) {
#pragma unroll
            for (int sp = 0; sp < KSPLIT; ++sp) {
                const float4 v =
                    *(const float4*)&hpart[((size_t)sp * NN + grow) * CC + col4];
                s.x += v.x; s.y += v.y; s.z += v.z; s.w += v.w;
            }
        }
        const float4 bb = *(const float4*)&b0[col4];
        s.x = eluf(s.x + bb.x); s.y = eluf(s.y + bb.y);
        s.z = eluf(s.z + bb.z); s.w = eluf(s.w + bb.w);
        *(float4*)&xs[row * 68 + col4] = s;
    }
    {
        const int sk = tid & 63;
        const int sr = tid >> 6;
#pragma unroll
        for (int i = 0; i < 16; ++i)
            ws[(sr + 4 * i) * 64 + sk] = w1[(sr + 4 * i) * CC + sk];
    }
    __syncthreads();

    const int cg = tid & 15;
    const int rg = tid >> 4;
    float acc2[2][4];
    const float4 b1v = *(const float4*)&b1[cg * 4];
#pragma unroll
    for (int j = 0; j < 2; ++j) {
        acc2[j][0] = b1v.x; acc2[j][1] = b1v.y;
        acc2[j][2] = b1v.z; acc2[j][3] = b1v.w;
    }
#pragma unroll 4
    for (int k4 = 0; k4 < 64; k4 += 4) {
        float4 xv[2], wv[4];
#pragma unroll
        for (int j = 0; j < 2; ++j)
            xv[j] = *(const float4*)&xs[(rg * 2 + j) * 68 + k4];
#pragma unroll
        for (int q = 0; q < 4; ++q)
            wv[q] = *(const float4*)&ws[(k4 + q) * 64 + cg * 4];
#pragma unroll
        for (int j = 0; j < 2; ++j) {
            const float* xf = (const float*)&xv[j];
#pragma unroll
            for (int q = 0; q < 4; ++q) {
                const float* wf = (const float*)&wv[q];
#pragma unroll
                for (int i = 0; i < 4; ++i)
                    acc2[j][i] = fmaf(xf[q], wf[i], acc2[j][i]);
            }
        }
    }

    __syncthreads();
#pragma unroll
    for (int j = 0; j < 2; ++j)
        *(float4*)&ws[(rg * 2 + j) * 64 + cg * 4] =
            make_float4(acc2[j][0], acc2[j][1], acc2[j][2], acc2[j][3]);
    __syncthreads();

    const int c = tid & 63;
    const int w = tid >> 6;
    const float ha = hop_att0[c];
    const float hb = hop_bias0[0];
#pragma unroll
    for (int rr = 0; rr < 8; ++rr) {
        const int r = w * 8 + rr;
        const float v = ws[r * 64 + c];
        const float attn = wave_sum(ha * eluf(v)) + hb;
        const int row = R0 + r;
        if (row < NN) {
            const float zv = v * attn;
            const float zs = zv * scale1;
            xout[row * CC + c] = (half_t)v;
            zout[row * CC + c] = zv;
            zsout[row * CC + c] = zs;
            zshout[row * CC + c] = (half_t)zs;
        }
    }
}

// pass 1: partition edges into 157 coarse buckets (dst>>6), pairs (src,dst).
__global__ __launch_bounds__(256) void k_part1(
    const int* __restrict__ ei, int* __restrict__ bcur,
    int2* __restrict__ csr_pair)
{
    __shared__ int hist[NBUCK];
    __shared__ int scan_s[NBUCK];
    __shared__ int base_g[NBUCK];
    __shared__ int lcur[NBUCK];
    __shared__ int2 staged[CHUNK];
    const int tid = threadIdx.x;
    const int e0 = blockIdx.x * CHUNK;

    for (int b = tid; b < NBUCK; b += 256) { hist[b] = 0; lcur[b] = 0; }
    __syncthreads();

    int src[8], dst[8];
#pragma unroll
    for (int j = 0; j < 8; ++j) {
        const int e = e0 + tid + 256 * j;
        if (e < EE) {
            src[j] = ei[e];
            dst[j] = ei[EE + e];
            atomicAdd(&hist[dst[j] >> 6], 1);
        } else dst[j] = -1;
    }
    __syncthreads();
    if (tid == 0) {
        int run = 0;
        for (int b = 0; b < NBUCK; ++b) { scan_s[b] = run; run += hist[b]; }
    }
    __syncthreads();
    if (tid < NBUCK && hist[tid] > 0)
        base_g[tid] = atomicAdd(&bcur[tid], hist[tid]);
    __syncthreads();
#pragma unroll
    for (int j = 0; j < 8; ++j) {
        if (dst[j] >= 0) {
            const int b = dst[j] >> 6;
            const int r = atomicAdd(&lcur[b], 1);
            staged[scan_s[b] + r] = make_int2(src[j], dst[j]);
        }
    }
    __syncthreads();
    const int tot = (EE - e0) < CHUNK ? (EE - e0) : CHUNK;
    for (int i = tid; i < tot; i += 256) {
        const int2 p = staged[i];
        const int b = p.y >> 6;
        csr_pair[base_g[b] + (i - scan_s[b])] = p;
    }
}

// pass 2: within each bucket, place each edge at its exact CSR slot.
__global__ __launch_bounds__(256) void k_part2(
    const int* __restrict__ offs, const int2* __restrict__ csr_pair,
    int* __restrict__ csr_src)
{
    __shared__ int lcnt[64];
    __shared__ int loffs[64];
    const int b = blockIdx.x;           // NBUCK blocks
    const int tid = threadIdx.x;
    const int d0 = b * 64;
    if (tid < 64) {
        lcnt[tid] = 0;
        const int d = d0 + tid;
        loffs[tid] = (d < NN) ? offs[d] : EE;
    }
    __syncthreads();
    const int r0 = offs[d0];
    const int r1 = (d0 + 64 < NN) ? offs[d0 + 64] : EE;
    for (int i = r0 + tid; i < r1; i += 256) {
        const int2 p = csr_pair[i];
        const int ld = p.y & 63;
        const int r = atomicAdd(&lcnt[ld], 1);
        csr_src[loffs[ld] + r] = p.x;
    }
}

// ---------------------------------------------------------------------------
// Fused edge attention + degree norm. One wave per block, one node, grid=NN.
// zs gathers fp16 (zsh); per-node zd fp32 (zsbuf) — r10-proven split.
// ---------------------------------------------------------------------------
__global__ __launch_bounds__(64) void k_edge_adj(
    const int* __restrict__ offs, const int* __restrict__ deg,
    const int* __restrict__ csr_src,
    const float* __restrict__ zs_buf, const half_t* __restrict__ zsh,
    const float* __restrict__ conv_att,
    float* __restrict__ a_csr, float* __restrict__ inv_adj)
{
    const int n = blockIdx.x;
    const int lane = threadIdx.x;
    const int l = lane & 15;
    const int grp = lane >> 4;
    const int start = offs[n];
    const int len = deg[n];

    const float4 zd = *(const float4*)(zs_buf + n * CC + l * 4);
    const float4 scv = *(const float4*)(conv_att + l * 4);

    float asum = 0.f;
    int i = grp;
    for (; i + 12 < len; i += 16) {      // 4 edges in flight per group
        const int s0 = csr_src[start + i];
        const int s1 = csr_src[start + i + 4];
        const int s2 = csr_src[start + i + 8];
        const int s3 = csr_src[start + i + 12];
        const float4 a0 = ldh4(zsh + s0 * CC + l * 4);
        const float4 a1 = ldh4(zsh + s1 * CC + l * 4);
        const float4 a2 = ldh4(zsh + s2 * CC + l * 4);
        const float4 a3 = ldh4(zsh + s3 * CC + l * 4);
        float p0 = scv.x * eluf(a0.x + zd.x);
        p0 = fmaf(scv.y, eluf(a0.y + zd.y), p0);
        p0 = fmaf(scv.z, eluf(a0.z + zd.z), p0);
        p0 = fmaf(scv.w, eluf(a0.w + zd.w), p0);
        float p1 = scv.x * eluf(a1.x + zd.x);
        p1 = fmaf(scv.y, eluf(a1.y + zd.y), p1);
        p1 = fmaf(scv.z, eluf(a1.z + zd.z), p1);
        p1 = fmaf(scv.w, eluf(a1.w + zd.w), p1);
        float p2 = scv.x * eluf(a2.x + zd.x);
        p2 = fmaf(scv.y, eluf(a2.y + zd.y), p2);
        p2 = fmaf(scv.z, eluf(a2.z + zd.z), p2);
        p2 = fmaf(scv.w, eluf(a2.w + zd.w), p2);
        float p3 = scv.x * eluf(a3.x + zd.x);
        p3 = fmaf(scv.y, eluf(a3.y + zd.y), p3);
        p3 = fmaf(scv.z, eluf(a3.z + zd.z), p3);
        p3 = fmaf(scv.w, eluf(a3.w + zd.w), p3);
#pragma unroll
        for (int off = 8; off > 0; off >>= 1) {
            p0 += __shfl_xor(p0, off, 64);
            p1 += __shfl_xor(p1, off, 64);
            p2 += __shfl_xor(p2, off, 64);
            p3 += __shfl_xor(p3, off, 64);
        }
        const float ae0 = softplusf(p0) + 1e-6f;
        const float ae1 = softplusf(p1) + 1e-6f;
        const float ae2 = softplusf(p2) + 1e-6f;
        const float ae3 = softplusf(p3) + 1e-6f;
        asum += ae0 + ae1 + ae2 + ae3;
        if (l == 0) {
            a_csr[start + i] = ae0;
            a_csr[start + i + 4] = ae1;
            a_csr[start + i + 8] = ae2;
            a_csr[start + i + 12] = ae3;
        }
    }
    for (; i < len; i += 4) {
        const int s0 = csr_src[start + i];
        const float4 a0 = ldh4(zsh + s0 * CC + l * 4);
        float p0 = scv.x * eluf(a0.x + zd.x);
        p0 = fmaf(scv.y, eluf(a0.y + zd.y), p0);
        p0 = fmaf(scv.z, eluf(a0.z + zd.z), p0);
        p0 = fmaf(scv.w, eluf(a0.w + zd.w), p0);
#pragma unroll
        for (int off = 8; off > 0; off >>= 1) p0 += __shfl_xor(p0, off, 64);
        const float ae0 = softplusf(p0) + 1e-6f;
        asum += ae0;
        if (l == 0) a_csr[start + i] = ae0;
    }

    asum += __shfl_xor(asum, 16, 64);
    asum += __shfl_xor(asum, 32, 64);
    if (lane == 0) inv_adj[n] = rsqrtf(fmaxf(asum, 1e-32f));
}

// ---------------------------------------------------------------------------
// Fused message gather + UpdateZ. One wave per block, one node, grid=NN.
// 8 row-gathers in flight; x gathers fp16. (r10-proven version)
// ---------------------------------------------------------------------------
__global__ __launch_bounds__(64) void k_msg_fused(
    const int* __restrict__ offs, const int* __restrict__ deg,
    const int* __restrict__ csr_src, const float* __restrict__ a_csr,
    const float* __restrict__ inv_adj, const half_t* __restrict__ x,
    half_t* __restrict__ xn, float* __restrict__ z,
    float* __restrict__ zs_buf, half_t* __restrict__ zsh,
    const float* __restrict__ hop_att, const float* __restrict__ hop_bias,
    float scale_next)
{
    const int n = blockIdx.x;
    const int c = threadIdx.x;
    const int start = offs[n];
    const int len = deg[n];
    const float invd = inv_adj[n];

    float acc = 0.f;
    for (int base = 0; base < len; base += 64) {
        const int cnt = (len - base) < 64 ? (len - base) : 64;
        int s_l = 0; float na_l = 0.f;
        if (c < cnt) {
            s_l = csr_src[start + base + c];
            na_l = a_csr[start + base + c] * inv_adj[s_l] * invd;
        }
        int j = 0;
        for (; j + 8 <= cnt; j += 8) {
            int ss[8]; float nn_[8];
#pragma unroll
            for (int q = 0; q < 8; ++q) {
                ss[q] = __builtin_amdgcn_readlane(s_l, j + q);
                nn_[q] = __int_as_float(
                    __builtin_amdgcn_readlane(__float_as_int(na_l), j + q));
            }
            float vv[8];
#pragma unroll
            for (int q = 0; q < 8; ++q) vv[q] = (float)x[ss[q] * CC + c];
#pragma unroll
            for (int q = 0; q < 8; ++q) acc = fmaf(vv[q], nn_[q], acc);
        }
        for (; j < cnt; ++j) {
            const int s = __builtin_amdgcn_readlane(s_l, j);
            const float na = __int_as_float(
                __builtin_amdgcn_readlane(__float_as_int(na_l), j));
            acc = fmaf((float)x[s * CC + c], na, acc);
        }
    }

    // UpdateZ (k >= 1): g = [h, z_scale]; z_scale is zs (already scaled)
    const float zv = z[n * CC + c];
    const float zsv = zs_buf[n * CC + c];
    float g = hop_att[c] * eluf(acc) + hop_att[CC + c] * eluf(zsv);
    const float attn = wave_sum(g) + hop_bias[0];
    const float znew = zv + acc * attn;
    const float zsnew = znew * scale_next;
    z[n * CC + c] = znew;
    zs_buf[n * CC + c] = zsnew;
    zsh[n * CC + c] = (half_t)zsnew;
    xn[n * CC + c] = (half_t)acc;
}

// ---------------------------------------------------------------------------
// Fused readout: block per graph.
// ---------------------------------------------------------------------------
__global__ __launch_bounds__(256) void k_pool_head(
    const float* __restrict__ z, const int* __restrict__ gstart,
    const float* __restrict__ w_head, const float* __restrict__ b_head,
    float* __restrict__ out)
{
    __shared__ float red[4][CC];
    const int g = blockIdx.x;
    const int w = threadIdx.x >> 6;
    const int c = threadIdx.x & 63;
    const int s0 = gstart[g], s1 = gstart[g + 1];

    float acc = 0.f;
    for (int n = s0 + w; n < s1; n += 4) acc += eluf(z[n * CC + c]);
    red[w][c] = acc;
    __syncthreads();
    if (w == 0) {
        const float v = red[0][c] + red[1][c] + red[2][c] + red[3][c];
        const float tot = wave_sum(v * w_head[c]);
        if (c == 0)
            out[g] = tot / fmaxf((float)(s1 - s0), 1.f) + b_head[0];
    }
}

extern "C" void kernel_launch(void* const* d_in, const int* in_sizes, int n_in,
                              void* d_out, int out_size, void* d_ws, size_t ws_size,
                              hipStream_t stream) {
    const float* x        = (const float*)d_in[0];
    const int*   ei       = (const int*)d_in[1];
    const int*   batch    = (const int*)d_in[2];
    const float* w0       = (const float*)d_in[3];
    const float* b0       = (const float*)d_in[4];
    const float* w1       = (const float*)d_in[5];
    const float* b1       = (const float*)d_in[6];
    const float* conv_att = (const float*)d_in[7];
    const float* hop_att0 = (const float*)d_in[8];
    const float* hop_bias0= (const float*)d_in[9];
    const float* hop_att  = (const float*)d_in[10];
    const float* hop_bias = (const float*)d_in[11];
    const float* w_head   = (const float*)d_in[12];
    const float* b_head   = (const float*)d_in[13];
    float* out = (float*)d_out;

    float sc[NLAYER + 1];
    for (int k = 1; k <= NLAYER; ++k)
        sc[k] = (float)log(1.0 / (double)k + 1.0 + 1e-6);

    // ---- flat workspace layout ----
    float* zbuf    = (float*)d_ws;               // NN*CC fp32
    float* zsbuf   = zbuf + NN * CC;             // NN*CC fp32
    float* inv_adj = zsbuf + NN * CC;            // NN
    float* hpart   = inv_adj + NN;               // KSPLIT*NN*CC
    float* a_csr   = hpart + (size_t)KSPLIT * NN * CC;  // EE
    int*   csr_src = (int*)(a_csr + EE);         // EE
    int2*  csr_pair= (int2*)(csr_src + EE);      // EE pairs
    int*   deg     = (int*)(csr_pair + EE);      // NN (zeroed)
    int*   offs    = deg + NN;                   // NN
    int*   bcur    = offs + NN;                  // NBUCK
    int*   gstart  = bcur + NBUCK;               // GG+1
    half_t* xhA = (half_t*)(gstart + GG + 1);    // NN*CC fp16
    half_t* xhB = xhA + NN * CC;                 // NN*CC fp16
    half_t* zsh = xhB + NN * CC;                 // NN*CC fp16

    (void)hipMemsetAsync(deg, 0, (size_t)NN * 4, stream);
    k_gemm1_hist<<<GEMM1B + HISTB, 256, 0, stream>>>(x, w0, hpart, ei, deg);
    k_init2_scan<<<314 + (NN + 255) / 256, 256, 0, stream>>>(
        hpart, b0, w1, b1, hop_att0, hop_bias0, sc[1],
        xhA, zbuf, zsbuf, zsh, deg, offs, bcur, batch, gstart);
    k_part1<<<(EE + CHUNK - 1) / CHUNK, 256, 0, stream>>>(ei, bcur, csr_pair);
    k_part2<<<NBUCK, 256, 0, stream>>>(offs, csr_pair, csr_src);

    half_t* xcur = xhA;
    half_t* xnext = xhB;
    for (int i = 0; i < NLAYER; ++i) {
        const float scale_next = (i + 1 < NLAYER) ? sc[i + 2] : 0.f;
        k_edge_adj<<<NN, 64, 0, stream>>>(offs, deg, csr_src, zsbuf, zsh,
                                          conv_att + i * CC,
                                          a_csr, inv_adj);
        k_msg_fused<<<NN, 64, 0, stream>>>(offs, deg, csr_src, a_csr,
                                           inv_adj, xcur, xnext, zbuf,
                                           zsbuf, zsh,
                                           hop_att + i * 2 * CC,
                                           hop_bias + i, scale_next);
        half_t* t = xcur; xcur = xnext; xnext = t;
    }

    k_pool_head<<<GG, 256, 0, stream>>>(zbuf, gstart, w_head, b_head, out);
}